// Round 1
// baseline (848.950 us; speedup 1.0000x reference)
//
#include <hip/hip_runtime.h>
#include <math.h>

#define N_NODES 50000
#define N_EDGES 800000
#define N_ETOT  850000          // + self loops
#define C_IN    128
#define C_HID   96
#define C_OUT   40
#define NEG_SLOPE 0.2f

__device__ __forceinline__ void atomicMaxFloat(float* addr, float val) {
    // valid because m is initialized to -inf; monotone int-punning trick
    if (val >= 0.f) atomicMax((int*)addr, __float_as_int(val));
    else            atomicMin((unsigned int*)addr, (unsigned int)__float_as_int(val));
}

__global__ void k_init(float* m1, float* s1, float* m2, float* s2,
                       float* agg1, float* agg2) {
    int i = blockIdx.x * blockDim.x + threadIdx.x;
    int stride = gridDim.x * blockDim.x;
    for (int j = i; j < N_NODES; j += stride) {
        m1[j] = -INFINITY; s1[j] = 0.f;
        m2[j] = -INFINITY; s2[j] = 0.f;
    }
    for (int j = i; j < N_NODES * C_HID; j += stride) agg1[j] = 0.f;
    for (int j = i; j < N_NODES * C_OUT; j += stride) agg2[j] = 0.f;
}

// h1 = x @ W1 ; as[n] = h1[n]·a_src ; ad[n] = h1[n]·a_dst
__global__ void k_gemm1(const float* __restrict__ x, const float* __restrict__ W,
                        const float* __restrict__ a_src, const float* __restrict__ a_dst,
                        float* __restrict__ h, float* __restrict__ as, float* __restrict__ ad) {
    __shared__ float xs[C_IN];
    __shared__ float ps[128], pd[128];
    int n = blockIdx.x;
    int t = threadIdx.x;
    xs[t] = x[n * C_IN + t];
    __syncthreads();
    float pps = 0.f, ppd = 0.f;
    if (t < C_HID) {
        float acc = 0.f;
        #pragma unroll 8
        for (int k = 0; k < C_IN; ++k) acc = fmaf(xs[k], W[k * C_HID + t], acc);
        h[n * C_HID + t] = acc;
        pps = acc * a_src[t];
        ppd = acc * a_dst[t];
    }
    ps[t] = pps; pd[t] = ppd;
    __syncthreads();
    for (int off = 64; off > 0; off >>= 1) {
        if (t < off) { ps[t] += ps[t + off]; pd[t] += pd[t + off]; }
        __syncthreads();
    }
    if (t == 0) { as[n] = ps[0]; ad[n] = pd[0]; }
}

__global__ void k_edge_max(const int* __restrict__ ei, const float* __restrict__ as,
                           const float* __restrict__ ad, float* __restrict__ e,
                           float* __restrict__ m) {
    int i = blockIdx.x * blockDim.x + threadIdx.x;
    if (i >= N_ETOT) return;
    int src, dst;
    if (i < N_EDGES) { src = ei[i]; dst = ei[N_EDGES + i]; }
    else             { src = dst = i - N_EDGES; }
    float v = as[src] + ad[dst];
    v = (v >= 0.f) ? v : NEG_SLOPE * v;
    e[i] = v;
    atomicMaxFloat(&m[dst], v);
}

__global__ void k_edge_exp(const int* __restrict__ ei, const float* __restrict__ m,
                           float* __restrict__ e, float* __restrict__ s) {
    int i = blockIdx.x * blockDim.x + threadIdx.x;
    if (i >= N_ETOT) return;
    int dst = (i < N_EDGES) ? ei[N_EDGES + i] : i - N_EDGES;
    float w = expf(e[i] - m[dst]);
    e[i] = w;
    atomicAdd(&s[dst], w);
}

// one 64-lane wave per edge; channels strided by lane
template <int C>
__global__ void k_aggregate(const int* __restrict__ ei, const float* __restrict__ h,
                            const float* __restrict__ e, const float* __restrict__ s,
                            float* __restrict__ agg) {
    int gid  = blockIdx.x * blockDim.x + threadIdx.x;
    int wid  = gid >> 6;
    int lane = threadIdx.x & 63;
    if (wid >= N_ETOT) return;
    int src, dst;
    if (wid < N_EDGES) { src = ei[wid]; dst = ei[N_EDGES + wid]; }
    else               { src = dst = wid - N_EDGES; }
    float alpha = e[wid] / s[dst];
    for (int c = lane; c < C; c += 64) {
        atomicAdd(&agg[dst * C + c], h[src * C + c] * alpha);
    }
}

// x2 = relu(agg1 + b1); h2 = x2 @ W2 ; alpha dots
__global__ void k_gemm2(const float* __restrict__ agg1, const float* __restrict__ b1,
                        const float* __restrict__ W, const float* __restrict__ a_src,
                        const float* __restrict__ a_dst, float* __restrict__ h,
                        float* __restrict__ as, float* __restrict__ ad) {
    __shared__ float xs[C_HID];
    __shared__ float ps[64], pd[64];
    int n = blockIdx.x, t = threadIdx.x;
    for (int k = t; k < C_HID; k += 64) {
        float v = agg1[n * C_HID + k] + b1[k];
        xs[k] = (v > 0.f) ? v : 0.f;
    }
    __syncthreads();
    float pps = 0.f, ppd = 0.f;
    if (t < C_OUT) {
        float acc = 0.f;
        #pragma unroll 8
        for (int k = 0; k < C_HID; ++k) acc = fmaf(xs[k], W[k * C_OUT + t], acc);
        h[n * C_OUT + t] = acc;
        pps = acc * a_src[t];
        ppd = acc * a_dst[t];
    }
    ps[t] = pps; pd[t] = ppd;
    __syncthreads();
    for (int off = 32; off > 0; off >>= 1) {
        if (t < off) { ps[t] += ps[t + off]; pd[t] += pd[t + off]; }
        __syncthreads();
    }
    if (t == 0) { as[n] = ps[0]; ad[n] = pd[0]; }
}

__global__ void k_final(const float* __restrict__ agg2, const float* __restrict__ b2,
                        float* __restrict__ out) {
    int n = blockIdx.x, t = threadIdx.x;
    float v  = (t < C_OUT) ? agg2[n * C_OUT + t] + b2[t] : -INFINITY;
    float mx = v;
    for (int off = 32; off > 0; off >>= 1) mx = fmaxf(mx, __shfl_xor(mx, off));
    float ex = (t < C_OUT) ? expf(v - mx) : 0.f;
    float sm = ex;
    for (int off = 32; off > 0; off >>= 1) sm += __shfl_xor(sm, off);
    if (t < C_OUT) out[n * C_OUT + t] = v - mx - logf(sm);
}

extern "C" void kernel_launch(void* const* d_in, const int* in_sizes, int n_in,
                              void* d_out, int out_size, void* d_ws, size_t ws_size,
                              hipStream_t stream) {
    const float* x      = (const float*)d_in[0];
    const int*   ei     = (const int*)d_in[1];
    // d_in[2] new_edge_indexs: unused by the reference
    const float* W1     = (const float*)d_in[3];
    const float* a_src1 = (const float*)d_in[4];
    const float* a_dst1 = (const float*)d_in[5];
    const float* b1     = (const float*)d_in[6];
    const float* W2     = (const float*)d_in[7];
    const float* a_src2 = (const float*)d_in[8];
    const float* a_dst2 = (const float*)d_in[9];
    const float* b2     = (const float*)d_in[10];
    float* out = (float*)d_out;

    float* ws = (float*)d_ws;
    size_t off = 0;
    float* h1   = ws + off; off += (size_t)N_NODES * C_HID;   // 4.8M
    float* agg1 = ws + off; off += (size_t)N_NODES * C_HID;   // 4.8M
    float* h2   = ws + off; off += (size_t)N_NODES * C_OUT;   // 2.0M
    float* agg2 = ws + off; off += (size_t)N_NODES * C_OUT;   // 2.0M
    float* e    = ws + off; off += (size_t)N_ETOT;            // 0.85M
    float* as1  = ws + off; off += N_NODES;
    float* ad1  = ws + off; off += N_NODES;
    float* m1   = ws + off; off += N_NODES;
    float* s1   = ws + off; off += N_NODES;
    float* as2  = ws + off; off += N_NODES;
    float* ad2  = ws + off; off += N_NODES;
    float* m2   = ws + off; off += N_NODES;
    float* s2   = ws + off; off += N_NODES;

    k_init<<<4096, 256, 0, stream>>>(m1, s1, m2, s2, agg1, agg2);

    // ---- layer 1 ----
    k_gemm1<<<N_NODES, 128, 0, stream>>>(x, W1, a_src1, a_dst1, h1, as1, ad1);
    int eb = (N_ETOT + 255) / 256;
    k_edge_max<<<eb, 256, 0, stream>>>(ei, as1, ad1, e, m1);
    k_edge_exp<<<eb, 256, 0, stream>>>(ei, m1, e, s1);
    int ab = (N_ETOT * 64 + 255) / 256;
    k_aggregate<C_HID><<<ab, 256, 0, stream>>>(ei, h1, e, s1, agg1);

    // ---- layer 2 ----
    k_gemm2<<<N_NODES, 64, 0, stream>>>(agg1, b1, W2, a_src2, a_dst2, h2, as2, ad2);
    k_edge_max<<<eb, 256, 0, stream>>>(ei, as2, ad2, e, m2);
    k_edge_exp<<<eb, 256, 0, stream>>>(ei, m2, e, s2);
    k_aggregate<C_OUT><<<ab, 256, 0, stream>>>(ei, h2, e, s2, agg2);

    k_final<<<N_NODES, 64, 0, stream>>>(agg2, b2, out);
}

// Round 2
// 534.549 us; speedup vs baseline: 1.5882x; 1.5882x over previous
//
#include <hip/hip_runtime.h>
#include <math.h>

#define N_NODES 50000
#define N_EDGES 800000
#define N_ETOT  850000          // + self loops
#define C_IN    128
#define C_HID   96
#define C_OUT   40
#define NEG_SLOPE 0.2f

// ---------------- CSR build ----------------

__global__ void k_initdeg(int* __restrict__ deg) {
    int i = blockIdx.x * blockDim.x + threadIdx.x;
    if (i < N_NODES) deg[i] = 1;            // self loop
}

__global__ void k_hist(const int* __restrict__ ei, int* __restrict__ deg) {
    int i = blockIdx.x * blockDim.x + threadIdx.x;
    if (i < N_EDGES) atomicAdd(&deg[ei[N_EDGES + i]], 1);
}

// single-block exclusive scan over deg -> row_ptr, cursor (wave shfl scan)
__global__ void k_scan(const int* __restrict__ deg, int* __restrict__ row_ptr,
                       int* __restrict__ cursor) {
    __shared__ int wsum[16];
    __shared__ int carry_s;
    const int t = threadIdx.x, lane = t & 63, w = t >> 6;
    if (t == 0) carry_s = 0;
    __syncthreads();
    for (int base = 0; base < N_NODES; base += 1024) {
        int i = base + t;
        int v = (i < N_NODES) ? deg[i] : 0;
        int inc = v;
        #pragma unroll
        for (int off = 1; off < 64; off <<= 1) {
            int u = __shfl_up(inc, off);
            if (lane >= off) inc += u;
        }
        if (lane == 63) wsum[w] = inc;
        __syncthreads();
        if (w == 0) {
            int sv = (lane < 16) ? wsum[lane] : 0;
            #pragma unroll
            for (int off = 1; off < 16; off <<= 1) {
                int u = __shfl_up(sv, off);
                if (lane >= off) sv += u;
            }
            if (lane < 16) wsum[lane] = sv;       // inclusive over waves
        }
        __syncthreads();
        int exc = carry_s + ((w == 0) ? 0 : wsum[w - 1]) + inc - v;
        if (i < N_NODES) { row_ptr[i] = exc; cursor[i] = exc; }
        __syncthreads();
        if (t == 0) carry_s += wsum[15];
        __syncthreads();
    }
    if (t == 0) row_ptr[N_NODES] = carry_s;       // == N_ETOT
}

__global__ void k_scatter(const int* __restrict__ ei, int* __restrict__ cursor,
                          int* __restrict__ csr_src) {
    int i = blockIdx.x * blockDim.x + threadIdx.x;
    if (i >= N_ETOT) return;
    int src, dst;
    if (i < N_EDGES) { src = ei[i]; dst = ei[N_EDGES + i]; }
    else             { src = dst = i - N_EDGES; }
    int pos = atomicAdd(&cursor[dst], 1);
    csr_src[pos] = src;
}

// ---------------- tiled GEMM: H[N, COUT] = X[N, CIN] @ W[CIN, COUT] ----------------
// block covers NPB=NT*NP nodes x COUT cols; thread tile NP nodes x 4 cols.
// x staged in LDS [NPB][CIN+1] (conflict-free column reads); W staged in KH-row chunks.

template<int CIN, int COUT, int KH, int CT, int NT, int NP>
__global__ __launch_bounds__(CT * NT)
void k_gemm(const float* __restrict__ X, const float* __restrict__ W,
            float* __restrict__ H) {
    constexpr int NPB = NT * NP;
    constexpr int BLK = CT * NT;
    constexpr int KQ  = CIN / 4;
    __shared__ float xs[NPB][CIN + 1];
    __shared__ float Ws[KH * COUT];
    const int t  = threadIdx.x;
    const int nb = blockIdx.x * NPB;

    for (int idx = t; idx < NPB * KQ; idx += BLK) {
        int n = idx / KQ, kq = idx - n * KQ;
        float4 v = make_float4(0.f, 0.f, 0.f, 0.f);
        if (nb + n < N_NODES)
            v = reinterpret_cast<const float4*>(X)[(size_t)(nb + n) * KQ + kq];
        xs[n][4 * kq + 0] = v.x; xs[n][4 * kq + 1] = v.y;
        xs[n][4 * kq + 2] = v.z; xs[n][4 * kq + 3] = v.w;
    }

    const int ct = t % CT, nt = t / CT;
    float acc[NP][4] = {};

    for (int kb = 0; kb < CIN; kb += KH) {
        __syncthreads();                                  // xs ready / Ws reusable
        for (int idx = t; idx < KH * COUT; idx += BLK) Ws[idx] = W[kb * COUT + idx];
        __syncthreads();
        #pragma unroll 4
        for (int kk = 0; kk < KH; ++kk) {
            int k = kb + kk;
            float4 wv = *reinterpret_cast<const float4*>(&Ws[kk * COUT + 4 * ct]);
            #pragma unroll
            for (int i = 0; i < NP; ++i) {
                float xv = xs[nt * NP + i][k];
                acc[i][0] = fmaf(xv, wv.x, acc[i][0]);
                acc[i][1] = fmaf(xv, wv.y, acc[i][1]);
                acc[i][2] = fmaf(xv, wv.z, acc[i][2]);
                acc[i][3] = fmaf(xv, wv.w, acc[i][3]);
            }
        }
    }

    #pragma unroll
    for (int i = 0; i < NP; ++i) {
        int n = nb + nt * NP + i;
        if (n < N_NODES) {
            float4 o = make_float4(acc[i][0], acc[i][1], acc[i][2], acc[i][3]);
            reinterpret_cast<float4*>(H)[(size_t)n * (COUT / 4) + ct] = o;
        }
    }
}

// ---------------- per-node alpha dots: as[n] = h[n]·a_src, ad[n] = h[n]·a_dst ----------------

template<int C>
__global__ void k_alpha(const float* __restrict__ h, const float* __restrict__ asrc,
                        const float* __restrict__ adst, float* __restrict__ as,
                        float* __restrict__ ad) {
    int n = blockIdx.x * 4 + (threadIdx.x >> 6);
    int lane = threadIdx.x & 63;
    float ps = 0.f, pd = 0.f;
    if (lane < C) {
        float v = h[(size_t)n * C + lane];
        ps = v * asrc[lane]; pd = v * adst[lane];
    }
    if (C > 64 && lane < C - 64) {
        float v = h[(size_t)n * C + 64 + lane];
        ps = fmaf(v, asrc[64 + lane], ps); pd = fmaf(v, adst[64 + lane], pd);
    }
    #pragma unroll
    for (int off = 32; off; off >>= 1) { ps += __shfl_xor(ps, off); pd += __shfl_xor(pd, off); }
    if (lane == 0) { as[n] = ps; ad[n] = pd; }
}

// ---------------- fused segment softmax + aggregation, one wave per dst node ----------------
// EPI 0: out = relu(agg + bias)   (layer-1 -> x2)
// EPI 1: out = log_softmax(agg + bias)  (layer-2 -> final output)

template<int C, int EPI>
__global__ void k_node_agg(const int* __restrict__ row_ptr, const int* __restrict__ csr_src,
                           const float* __restrict__ as, const float* __restrict__ ad,
                           const float* __restrict__ h, const float* __restrict__ bias,
                           float* __restrict__ outp) {
    int n = blockIdx.x * 4 + (threadIdx.x >> 6);
    int lane = threadIdx.x & 63;
    int beg = row_ptr[n], end = row_ptr[n + 1];
    float adn = ad[n];

    // pass 1: segment max, lane-parallel over edges
    float mx = -INFINITY;
    for (int j = beg + lane; j < end; j += 64) {
        float v = as[csr_src[j]] + adn;
        v = (v >= 0.f) ? v : NEG_SLOPE * v;
        mx = fmaxf(mx, v);
    }
    #pragma unroll
    for (int off = 32; off; off >>= 1) mx = fmaxf(mx, __shfl_xor(mx, off));

    // pass 2: sequential edges; lanes cover channels
    float s = 0.f, acc0 = 0.f, acc1 = 0.f;
    for (int j = beg; j < end; ++j) {
        int src = csr_src[j];
        float v = as[src] + adn;
        v = (v >= 0.f) ? v : NEG_SLOPE * v;
        float w = __expf(v - mx);
        s += w;                                   // identical on all lanes
        if (lane < C)              acc0 = fmaf(w, h[(size_t)src * C + lane], acc0);
        if (C > 64 && lane < C-64) acc1 = fmaf(w, h[(size_t)src * C + 64 + lane], acc1);
    }
    float inv = 1.f / s;

    if (EPI == 0) {
        if (lane < C) {
            float v = fmaf(acc0, inv, bias[lane]);
            outp[(size_t)n * C + lane] = fmaxf(v, 0.f);
        }
        if (C > 64 && lane < C - 64) {
            float v = fmaf(acc1, inv, bias[64 + lane]);
            outp[(size_t)n * C + 64 + lane] = fmaxf(v, 0.f);
        }
    } else {
        float v = (lane < C) ? fmaf(acc0, inv, bias[lane]) : -INFINITY;
        float m2 = v;
        #pragma unroll
        for (int off = 32; off; off >>= 1) m2 = fmaxf(m2, __shfl_xor(m2, off));
        float ex = (lane < C) ? __expf(v - m2) : 0.f;
        float sm = ex;
        #pragma unroll
        for (int off = 32; off; off >>= 1) sm += __shfl_xor(sm, off);
        if (lane < C) outp[(size_t)n * C + lane] = v - m2 - logf(sm);
    }
}

// ---------------- launch ----------------

extern "C" void kernel_launch(void* const* d_in, const int* in_sizes, int n_in,
                              void* d_out, int out_size, void* d_ws, size_t ws_size,
                              hipStream_t stream) {
    const float* x      = (const float*)d_in[0];
    const int*   ei     = (const int*)d_in[1];
    const float* W1     = (const float*)d_in[3];
    const float* a_src1 = (const float*)d_in[4];
    const float* a_dst1 = (const float*)d_in[5];
    const float* b1     = (const float*)d_in[6];
    const float* W2     = (const float*)d_in[7];
    const float* a_src2 = (const float*)d_in[8];
    const float* a_dst2 = (const float*)d_in[9];
    const float* b2     = (const float*)d_in[10];
    float* out = (float*)d_out;

    float* wsf = (float*)d_ws;
    size_t off = 0;
    float* h1  = wsf + off; off += (size_t)N_NODES * C_HID;   // 4.8M
    float* x2  = wsf + off; off += (size_t)N_NODES * C_HID;   // 4.8M
    float* h2  = wsf + off; off += (size_t)N_NODES * C_OUT;   // 2.0M
    float* as1 = wsf + off; off += N_NODES;
    float* ad1 = wsf + off; off += N_NODES;
    float* as2 = wsf + off; off += N_NODES;
    float* ad2 = wsf + off; off += N_NODES;
    int* wsi     = (int*)(wsf + off);
    size_t ioff  = 0;
    int* deg     = wsi + ioff; ioff += N_NODES;
    int* row_ptr = wsi + ioff; ioff += N_NODES + 1;
    int* cursor  = wsi + ioff; ioff += N_NODES;
    int* csr_src = wsi + ioff; ioff += N_ETOT;

    // CSR build (shared by both layers)
    k_initdeg<<<(N_NODES + 255) / 256, 256, 0, stream>>>(deg);
    k_hist<<<(N_EDGES + 255) / 256, 256, 0, stream>>>(ei, deg);
    k_scan<<<1, 1024, 0, stream>>>(deg, row_ptr, cursor);
    k_scatter<<<(N_ETOT + 255) / 256, 256, 0, stream>>>(ei, cursor, csr_src);

    // layer 1
    k_gemm<C_IN, C_HID, 64, 24, 8, 4><<<(N_NODES + 31) / 32, 192, 0, stream>>>(x, W1, h1);
    k_alpha<C_HID><<<N_NODES / 4, 256, 0, stream>>>(h1, a_src1, a_dst1, as1, ad1);
    k_node_agg<C_HID, 0><<<N_NODES / 4, 256, 0, stream>>>(row_ptr, csr_src, as1, ad1, h1, b1, x2);

    // layer 2
    k_gemm<C_HID, C_OUT, 96, 10, 32, 2><<<(N_NODES + 63) / 64, 320, 0, stream>>>(x2, W2, h2);
    k_alpha<C_OUT><<<N_NODES / 4, 256, 0, stream>>>(h2, a_src2, a_dst2, as2, ad2);
    k_node_agg<C_OUT, 1><<<N_NODES / 4, 256, 0, stream>>>(row_ptr, csr_src, as2, ad2, h2, b2, out);
}

// Round 4
// 347.617 us; speedup vs baseline: 2.4422x; 1.5378x over previous
//
#include <hip/hip_runtime.h>
#include <math.h>

#define N_NODES 50000
#define N_EDGES 800000
#define N_ETOT  850000          // + self loops
#define C_IN    128
#define C_HID   96
#define C_OUT   40
#define NEG_SLOPE 0.2f
#define NSB ((N_NODES + 1023) / 1024)   // 49 scan blocks

// ---------------- CSR build ----------------

__global__ void k_initdeg(int* __restrict__ deg) {
    int i = blockIdx.x * blockDim.x + threadIdx.x;
    if (i < N_NODES) deg[i] = 1;            // self loop
}

__global__ void k_hist(const int* __restrict__ ei, int* __restrict__ deg) {
    int i = blockIdx.x * blockDim.x + threadIdx.x;
    if (i < N_EDGES) atomicAdd(&deg[ei[N_EDGES + i]], 1);
}

// hierarchical exclusive scan: per-block scan -> scan of block sums -> add offsets
__global__ void k_scan1(const int* __restrict__ deg, int* __restrict__ rp,
                        int* __restrict__ bsum) {
    __shared__ int wsum[16];
    int t = threadIdx.x, lane = t & 63, w = t >> 6;
    int i = blockIdx.x * 1024 + t;
    int v = (i < N_NODES) ? deg[i] : 0;
    int inc = v;
    #pragma unroll
    for (int off = 1; off < 64; off <<= 1) {
        int u = __shfl_up(inc, off);
        if (lane >= off) inc += u;
    }
    if (lane == 63) wsum[w] = inc;
    __syncthreads();
    if (w == 0) {
        int sv = (lane < 16) ? wsum[lane] : 0;
        #pragma unroll
        for (int off = 1; off < 16; off <<= 1) {
            int u = __shfl_up(sv, off);
            if (lane >= off) sv += u;
        }
        if (lane < 16) wsum[lane] = sv;       // inclusive over waves
    }
    __syncthreads();
    int exc = ((w == 0) ? 0 : wsum[w - 1]) + inc - v;
    if (i < N_NODES) rp[i] = exc;
    if (t == 0) bsum[blockIdx.x] = wsum[15];
}

__global__ void k_scan2(const int* __restrict__ bsum, int* __restrict__ boff,
                        int* __restrict__ rp) {
    int lane = threadIdx.x;   // 64 threads
    int v = (lane < NSB) ? bsum[lane] : 0;
    int inc = v;
    #pragma unroll
    for (int off = 1; off < 64; off <<= 1) {
        int u = __shfl_up(inc, off);
        if (lane >= off) inc += u;
    }
    if (lane < NSB) boff[lane] = inc - v;
    if (lane == 63) rp[N_NODES] = inc;        // total == N_ETOT
}

__global__ void k_scan3(int* __restrict__ rp, const int* __restrict__ boff,
                        int* __restrict__ cursor) {
    int i = blockIdx.x * blockDim.x + threadIdx.x;
    if (i < N_NODES) {
        int v = rp[i] + boff[i >> 10];
        rp[i] = v; cursor[i] = v;
    }
}

__global__ void k_scatter(const int* __restrict__ ei, int* __restrict__ cursor,
                          int* __restrict__ csr_src) {
    int i = blockIdx.x * blockDim.x + threadIdx.x;
    if (i >= N_ETOT) return;
    int src, dst;
    if (i < N_EDGES) { src = ei[i]; dst = ei[N_EDGES + i]; }
    else             { src = dst = i - N_EDGES; }
    int pos = atomicAdd(&cursor[dst], 1);
    csr_src[pos] = src;
}

// ---------------- tiled GEMM + fused alpha dots ----------------
// H[N, COUT] = X[N, CIN] @ W[CIN, COUT]; as[n]=H[n]·asrc; ad[n]=H[n]·adst

template<int CIN, int COUT, int KH, int CT, int NT, int NP>
__global__ __launch_bounds__(CT * NT)
void k_gemm(const float* __restrict__ X, const float* __restrict__ W,
            const float* __restrict__ asrc, const float* __restrict__ adst,
            float* __restrict__ H, float* __restrict__ as, float* __restrict__ ad) {
    constexpr int NPB = NT * NP;
    constexpr int BLK = CT * NT;
    constexpr int KQ  = CIN / 4;
    constexpr int CQ  = COUT / 4;
    __shared__ float xs[NPB][CIN + 1];
    __shared__ float4 Ws4[KH][CQ + 1];     // +1 f4 pad: row-to-row bank shift
    __shared__ float red[NPB * 2];
    const int t  = threadIdx.x;
    const int nb = blockIdx.x * NPB;

    for (int idx = t; idx < NPB * 2; idx += BLK) red[idx] = 0.f;

    for (int idx = t; idx < NPB * KQ; idx += BLK) {
        int n = idx / KQ, kq = idx - n * KQ;
        float4 v = make_float4(0.f, 0.f, 0.f, 0.f);
        if (nb + n < N_NODES)
            v = reinterpret_cast<const float4*>(X)[(size_t)(nb + n) * KQ + kq];
        xs[n][4 * kq + 0] = v.x; xs[n][4 * kq + 1] = v.y;
        xs[n][4 * kq + 2] = v.z; xs[n][4 * kq + 3] = v.w;
    }

    const int ct = t % CT, nt = t / CT;
    float acc[NP][4] = {};

    for (int kb = 0; kb < CIN; kb += KH) {
        __syncthreads();                    // xs ready / Ws reusable
        for (int idx = t; idx < KH * CQ; idx += BLK) {
            int kk = idx / CQ, c4 = idx - kk * CQ;
            Ws4[kk][c4] = reinterpret_cast<const float4*>(W)[(size_t)(kb + kk) * CQ + c4];
        }
        __syncthreads();
        #pragma unroll 4
        for (int kk = 0; kk < KH; ++kk) {
            float4 wv = Ws4[kk][ct];
            #pragma unroll
            for (int i = 0; i < NP; ++i) {
                float xv = xs[nt * NP + i][kb + kk];
                acc[i][0] = fmaf(xv, wv.x, acc[i][0]);
                acc[i][1] = fmaf(xv, wv.y, acc[i][1]);
                acc[i][2] = fmaf(xv, wv.z, acc[i][2]);
                acc[i][3] = fmaf(xv, wv.w, acc[i][3]);
            }
        }
    }

    // epilogue: H write + alpha partial dots via LDS float atomics
    float a0 = asrc[4*ct], a1 = asrc[4*ct+1], a2 = asrc[4*ct+2], a3 = asrc[4*ct+3];
    float d0 = adst[4*ct], d1 = adst[4*ct+1], d2 = adst[4*ct+2], d3 = adst[4*ct+3];
    #pragma unroll
    for (int i = 0; i < NP; ++i) {
        int n = nb + nt * NP + i;
        float pa = acc[i][0]*a0 + acc[i][1]*a1 + acc[i][2]*a2 + acc[i][3]*a3;
        float pd = acc[i][0]*d0 + acc[i][1]*d1 + acc[i][2]*d2 + acc[i][3]*d3;
        atomicAdd(&red[2 * (nt * NP + i)    ], pa);
        atomicAdd(&red[2 * (nt * NP + i) + 1], pd);
        if (n < N_NODES) {
            float4 o = make_float4(acc[i][0], acc[i][1], acc[i][2], acc[i][3]);
            reinterpret_cast<float4*>(H)[(size_t)n * CQ + ct] = o;
        }
    }
    __syncthreads();
    for (int idx = t; idx < NPB; idx += BLK) {
        int n = nb + idx;
        if (n < N_NODES) { as[n] = red[2 * idx]; ad[n] = red[2 * idx + 1]; }
    }
}

// ---------------- fused segment softmax + aggregation, one wave per dst ----------------
// Multi-edge slots: 64 lanes = SLOTS edges x CV float4-channels, unroll x2.
// EPI 0: out = relu(agg + bias); EPI 1: out = log_softmax(agg + bias)

template<int C, int EPI>
__global__ __launch_bounds__(256)
void k_node_agg(const int* __restrict__ row_ptr, const int* __restrict__ csr_src,
                const float* __restrict__ as, const float* __restrict__ ad,
                const float* __restrict__ h, const float* __restrict__ bias,
                float* __restrict__ outp) {
    constexpr int CV    = C / 4;        // float4 per feature row (24 or 10)
    constexpr int SLOTS = 64 / CV;      // edges per wave step (2 or 6)
    int n = blockIdx.x * 4 + (threadIdx.x >> 6);
    int lane = threadIdx.x & 63;
    int beg = row_ptr[n], end = row_ptr[n + 1];
    float adn = ad[n];

    // pass 1: segment max, lane-parallel over edges
    float mx = -INFINITY;
    for (int j = beg + lane; j < end; j += 64) {
        float v = as[csr_src[j]] + adn;
        v = (v >= 0.f) ? v : NEG_SLOPE * v;
        mx = fmaxf(mx, v);
    }
    #pragma unroll
    for (int off = 32; off; off >>= 1) mx = fmaxf(mx, __shfl_xor(mx, off));

    // pass 2: SLOTS edges per step, float4 gather per lane, unrolled x2
    const int slot = lane / CV;
    const int c    = lane - slot * CV;
    const float4* h4 = reinterpret_cast<const float4*>(h);

    float4 acc = make_float4(0.f, 0.f, 0.f, 0.f);
    float s_lane = 0.f;

    for (int j = beg; j < end; j += 2 * SLOTS) {
        int j0 = j + slot, j1 = j + SLOTS + slot;
        bool a0 = (slot < SLOTS) && (j0 < end);
        bool a1 = (slot < SLOTS) && (j1 < end);
        int s0 = a0 ? csr_src[j0] : 0;
        int s1 = a1 ? csr_src[j1] : 0;
        float4 g0 = make_float4(0.f,0.f,0.f,0.f), g1 = make_float4(0.f,0.f,0.f,0.f);
        if (a0) g0 = h4[(size_t)s0 * CV + c];
        if (a1) g1 = h4[(size_t)s1 * CV + c];
        float v0 = as[s0] + adn; v0 = (v0 >= 0.f) ? v0 : NEG_SLOPE * v0;
        float v1 = as[s1] + adn; v1 = (v1 >= 0.f) ? v1 : NEG_SLOPE * v1;
        float w0 = a0 ? __expf(v0 - mx) : 0.f;
        float w1 = a1 ? __expf(v1 - mx) : 0.f;
        if (c == 0) s_lane += w0 + w1;
        acc.x = fmaf(w0, g0.x, acc.x); acc.y = fmaf(w0, g0.y, acc.y);
        acc.z = fmaf(w0, g0.z, acc.z); acc.w = fmaf(w0, g0.w, acc.w);
        acc.x = fmaf(w1, g1.x, acc.x); acc.y = fmaf(w1, g1.y, acc.y);
        acc.z = fmaf(w1, g1.z, acc.z); acc.w = fmaf(w1, g1.w, acc.w);
    }

    // fold slot accumulators into lanes [0, CV): gather from IMMUTABLE acc.
    // (stride-doubling tree is invalid for non-pow2 SLOTS — caused R2 failure)
    float4 tot = acc;
    #pragma unroll
    for (int s = 1; s < SLOTS; ++s) {
        int sl = (lane + CV * s) & 63;      // for lane<CV never wraps
        tot.x += __shfl(acc.x, sl); tot.y += __shfl(acc.y, sl);
        tot.z += __shfl(acc.z, sl); tot.w += __shfl(acc.w, sl);
    }
    float s = s_lane;
    #pragma unroll
    for (int off = 32; off; off >>= 1) s += __shfl_xor(s, off);
    float inv = 1.f / s;

    const float4* b4 = reinterpret_cast<const float4*>(bias);
    if (EPI == 0) {
        if (lane < CV) {
            float4 bb = b4[lane];
            float4 o;
            o.x = fmaxf(fmaf(tot.x, inv, bb.x), 0.f);
            o.y = fmaxf(fmaf(tot.y, inv, bb.y), 0.f);
            o.z = fmaxf(fmaf(tot.z, inv, bb.z), 0.f);
            o.w = fmaxf(fmaf(tot.w, inv, bb.w), 0.f);
            reinterpret_cast<float4*>(outp)[(size_t)n * CV + lane] = o;
        }
    } else {
        bool actw = lane < CV;
        float4 v4 = make_float4(-INFINITY, -INFINITY, -INFINITY, -INFINITY);
        if (actw) {
            float4 bb = b4[lane];
            v4.x = fmaf(tot.x, inv, bb.x); v4.y = fmaf(tot.y, inv, bb.y);
            v4.z = fmaf(tot.z, inv, bb.z); v4.w = fmaf(tot.w, inv, bb.w);
        }
        float vm = fmaxf(fmaxf(v4.x, v4.y), fmaxf(v4.z, v4.w));
        #pragma unroll
        for (int off = 32; off; off >>= 1) vm = fmaxf(vm, __shfl_xor(vm, off));
        float es = actw ? (__expf(v4.x - vm) + __expf(v4.y - vm) +
                           __expf(v4.z - vm) + __expf(v4.w - vm)) : 0.f;
        #pragma unroll
        for (int off = 32; off; off >>= 1) es += __shfl_xor(es, off);
        float lse = vm + logf(es);
        if (actw) {
            float4 o = make_float4(v4.x - lse, v4.y - lse, v4.z - lse, v4.w - lse);
            reinterpret_cast<float4*>(outp)[(size_t)n * CV + lane] = o;
        }
    }
}

// ---------------- launch ----------------

extern "C" void kernel_launch(void* const* d_in, const int* in_sizes, int n_in,
                              void* d_out, int out_size, void* d_ws, size_t ws_size,
                              hipStream_t stream) {
    const float* x      = (const float*)d_in[0];
    const int*   ei     = (const int*)d_in[1];
    const float* W1     = (const float*)d_in[3];
    const float* a_src1 = (const float*)d_in[4];
    const float* a_dst1 = (const float*)d_in[5];
    const float* b1     = (const float*)d_in[6];
    const float* W2     = (const float*)d_in[7];
    const float* a_src2 = (const float*)d_in[8];
    const float* a_dst2 = (const float*)d_in[9];
    const float* b2     = (const float*)d_in[10];
    float* out = (float*)d_out;

    float* wsf = (float*)d_ws;
    size_t off = 0;
    float* h1  = wsf + off; off += (size_t)N_NODES * C_HID;
    float* x2  = wsf + off; off += (size_t)N_NODES * C_HID;
    float* h2  = wsf + off; off += (size_t)N_NODES * C_OUT;
    float* as1 = wsf + off; off += N_NODES;
    float* ad1 = wsf + off; off += N_NODES;
    float* as2 = wsf + off; off += N_NODES;
    float* ad2 = wsf + off; off += N_NODES;
    int* wsi     = (int*)(wsf + off);
    size_t ioff  = 0;
    int* deg     = wsi + ioff; ioff += N_NODES;
    int* row_ptr = wsi + ioff; ioff += N_NODES + 1;
    int* cursor  = wsi + ioff; ioff += N_NODES;
    int* csr_src = wsi + ioff; ioff += N_ETOT;
    int* bsum    = wsi + ioff; ioff += NSB;
    int* boff    = wsi + ioff; ioff += NSB;

    // CSR build (shared by both layers)
    k_initdeg<<<(N_NODES + 255) / 256, 256, 0, stream>>>(deg);
    k_hist<<<(N_EDGES + 255) / 256, 256, 0, stream>>>(ei, deg);
    k_scan1<<<NSB, 1024, 0, stream>>>(deg, row_ptr, bsum);
    k_scan2<<<1, 64, 0, stream>>>(bsum, boff, row_ptr);
    k_scan3<<<(N_NODES + 1023) / 1024, 1024, 0, stream>>>(row_ptr, boff, cursor);
    k_scatter<<<(N_ETOT + 255) / 256, 256, 0, stream>>>(ei, cursor, csr_src);

    // layer 1
    k_gemm<C_IN, C_HID, 32, 24, 8, 4><<<(N_NODES + 31) / 32, 192, 0, stream>>>(
        x, W1, a_src1, a_dst1, h1, as1, ad1);
    k_node_agg<C_HID, 0><<<N_NODES / 4, 256, 0, stream>>>(row_ptr, csr_src, as1, ad1, h1, b1, x2);

    // layer 2
    k_gemm<C_HID, C_OUT, 96, 10, 32, 2><<<(N_NODES + 63) / 64, 320, 0, stream>>>(
        x2, W2, a_src2, a_dst2, h2, as2, ad2);
    k_node_agg<C_OUT, 1><<<N_NODES / 4, 256, 0, stream>>>(row_ptr, csr_src, as2, ad2, h2, b2, out);
}

// Round 8
// 322.719 us; speedup vs baseline: 2.6306x; 1.0772x over previous
//
#include <hip/hip_runtime.h>
#include <math.h>

#define N_NODES 50000
#define N_EDGES 800000
#define N_ETOT  850000          // + self loops
#define C_IN    128
#define C_HID   96
#define C_OUT   40
#define NEG_SLOPE 0.2f
#define NSB ((N_NODES + 1023) / 1024)   // 49 scan blocks

// ---------------- bf16 helpers ----------------
__device__ __forceinline__ unsigned short f2bf(float f) {
    unsigned u = __float_as_uint(f);
    u = u + 0x7fffu + ((u >> 16) & 1u);     // round-to-nearest-even
    return (unsigned short)(u >> 16);
}
__device__ __forceinline__ float bfu_lo(unsigned g) { return __uint_as_float(g << 16); }
__device__ __forceinline__ float bfu_hi(unsigned g) { return __uint_as_float(g & 0xffff0000u); }

// ---------------- CSR build ----------------

__global__ void k_initdeg(int* __restrict__ deg) {
    int i = blockIdx.x * blockDim.x + threadIdx.x;
    if (i < N_NODES) deg[i] = 1;            // self loop
}

__global__ void k_hist(const int* __restrict__ ei, int* __restrict__ deg) {
    int i = blockIdx.x * blockDim.x + threadIdx.x;
    if (i < N_EDGES) atomicAdd(&deg[ei[N_EDGES + i]], 1);
}

// hierarchical exclusive scan: per-block scan -> scan of block sums -> add offsets
__global__ void k_scan1(const int* __restrict__ deg, int* __restrict__ rp,
                        int* __restrict__ bsum) {
    __shared__ int wsum[16];
    int t = threadIdx.x, lane = t & 63, w = t >> 6;
    int i = blockIdx.x * 1024 + t;
    int v = (i < N_NODES) ? deg[i] : 0;
    int inc = v;
    #pragma unroll
    for (int off = 1; off < 64; off <<= 1) {
        int u = __shfl_up(inc, off);
        if (lane >= off) inc += u;
    }
    if (lane == 63) wsum[w] = inc;
    __syncthreads();
    if (w == 0) {
        int sv = (lane < 16) ? wsum[lane] : 0;
        #pragma unroll
        for (int off = 1; off < 16; off <<= 1) {
            int u = __shfl_up(sv, off);
            if (lane >= off) sv += u;
        }
        if (lane < 16) wsum[lane] = sv;       // inclusive over waves
    }
    __syncthreads();
    int exc = ((w == 0) ? 0 : wsum[w - 1]) + inc - v;
    if (i < N_NODES) rp[i] = exc;
    if (t == 0) bsum[blockIdx.x] = wsum[15];
}

__global__ void k_scan2(const int* __restrict__ bsum, int* __restrict__ boff,
                        int* __restrict__ rp) {
    int lane = threadIdx.x;   // 64 threads
    int v = (lane < NSB) ? bsum[lane] : 0;
    int inc = v;
    #pragma unroll
    for (int off = 1; off < 64; off <<= 1) {
        int u = __shfl_up(inc, off);
        if (lane >= off) inc += u;
    }
    if (lane < NSB) boff[lane] = inc - v;
    if (lane == 63) rp[N_NODES] = inc;        // total == N_ETOT
}

__global__ void k_scan3(int* __restrict__ rp, const int* __restrict__ boff,
                        int* __restrict__ cursor) {
    int i = blockIdx.x * blockDim.x + threadIdx.x;
    if (i < N_NODES) {
        int v = rp[i] + boff[i >> 10];
        rp[i] = v; cursor[i] = v;
    }
}

__global__ void k_scatter(const int* __restrict__ ei, int* __restrict__ cursor,
                          int* __restrict__ csr_src) {
    int i = blockIdx.x * blockDim.x + threadIdx.x;
    if (i >= N_ETOT) return;
    int src, dst;
    if (i < N_EDGES) { src = ei[i]; dst = ei[N_EDGES + i]; }
    else             { src = dst = i - N_EDGES; }
    int pos = atomicAdd(&cursor[dst], 1);
    csr_src[pos] = src;
}

// ---------------- tiled GEMM + fused alpha dots, bf16 H output ----------------
// H[N, COUT](bf16) = X[N, CIN] @ W[CIN, COUT]; as[n]=H[n]·asrc; ad[n]=H[n]·adst (fp32)

template<int CIN, int COUT, int KH, int CT, int NT, int NP>
__global__ __launch_bounds__(CT * NT)
void k_gemm(const float* __restrict__ X, const float* __restrict__ W,
            const float* __restrict__ asrc, const float* __restrict__ adst,
            unsigned short* __restrict__ Hb, float* __restrict__ as, float* __restrict__ ad) {
    constexpr int NPB = NT * NP;
    constexpr int BLK = CT * NT;
    constexpr int KQ  = CIN / 4;
    constexpr int CQ  = COUT / 4;
    __shared__ float xs[NPB][CIN + 1];
    __shared__ float4 Ws4[KH][CQ + 1];     // +1 f4 pad: row-to-row bank shift
    __shared__ float red[NPB * 2];
    const int t  = threadIdx.x;
    const int nb = blockIdx.x * NPB;

    for (int idx = t; idx < NPB * 2; idx += BLK) red[idx] = 0.f;

    for (int idx = t; idx < NPB * KQ; idx += BLK) {
        int n = idx / KQ, kq = idx - n * KQ;
        float4 v = make_float4(0.f, 0.f, 0.f, 0.f);
        if (nb + n < N_NODES)
            v = reinterpret_cast<const float4*>(X)[(size_t)(nb + n) * KQ + kq];
        xs[n][4 * kq + 0] = v.x; xs[n][4 * kq + 1] = v.y;
        xs[n][4 * kq + 2] = v.z; xs[n][4 * kq + 3] = v.w;
    }

    const int ct = t % CT, nt = t / CT;
    float acc[NP][4] = {};

    for (int kb = 0; kb < CIN; kb += KH) {
        __syncthreads();                    // xs ready / Ws reusable
        for (int idx = t; idx < KH * CQ; idx += BLK) {
            int kk = idx / CQ, c4 = idx - kk * CQ;
            Ws4[kk][c4] = reinterpret_cast<const float4*>(W)[(size_t)(kb + kk) * CQ + c4];
        }
        __syncthreads();
        #pragma unroll 4
        for (int kk = 0; kk < KH; ++kk) {
            float4 wv = Ws4[kk][ct];
            #pragma unroll
            for (int i = 0; i < NP; ++i) {
                float xv = xs[nt * NP + i][kb + kk];
                acc[i][0] = fmaf(xv, wv.x, acc[i][0]);
                acc[i][1] = fmaf(xv, wv.y, acc[i][1]);
                acc[i][2] = fmaf(xv, wv.z, acc[i][2]);
                acc[i][3] = fmaf(xv, wv.w, acc[i][3]);
            }
        }
    }

    // epilogue: bf16 H write + alpha partial dots via LDS float atomics (fp32)
    float a0 = asrc[4*ct], a1 = asrc[4*ct+1], a2 = asrc[4*ct+2], a3 = asrc[4*ct+3];
    float d0 = adst[4*ct], d1 = adst[4*ct+1], d2 = adst[4*ct+2], d3 = adst[4*ct+3];
    #pragma unroll
    for (int i = 0; i < NP; ++i) {
        int n = nb + nt * NP + i;
        float pa = acc[i][0]*a0 + acc[i][1]*a1 + acc[i][2]*a2 + acc[i][3]*a3;
        float pd = acc[i][0]*d0 + acc[i][1]*d1 + acc[i][2]*d2 + acc[i][3]*d3;
        atomicAdd(&red[2 * (nt * NP + i)    ], pa);
        atomicAdd(&red[2 * (nt * NP + i) + 1], pd);
        if (n < N_NODES) {
            ushort4 o;
            o.x = f2bf(acc[i][0]); o.y = f2bf(acc[i][1]);
            o.z = f2bf(acc[i][2]); o.w = f2bf(acc[i][3]);
            reinterpret_cast<ushort4*>(Hb)[(size_t)n * CQ + ct] = o;
        }
    }
    __syncthreads();
    for (int idx = t; idx < NPB; idx += BLK) {
        int n = nb + idx;
        if (n < N_NODES) { as[n] = red[2 * idx]; ad[n] = red[2 * idx + 1]; }
    }
}

// ---------------- fused segment softmax + aggregation, one wave per dst ----------------
// bf16 h gather. Per 64-edge chunk: all lanes compute w=exp(leaky(as+ad)-mx) once
// (1 exp + 1 random as-load per edge per wave), then gather distributes src/w by shfl.
// VEC channels per lane (16B int4 for VEC=8, 8B uint2 for VEC=4); SLOTS edges in parallel.
// EPI 0: out = relu(agg + bias); EPI 1: out = log_softmax(agg + bias)

template<int C, int VEC, int UN, int EPI>
__global__ __launch_bounds__(256)
void k_node_agg(const int* __restrict__ rp, const int* __restrict__ csr_src,
                const float* __restrict__ as, const float* __restrict__ ad,
                const void* __restrict__ hv, const float* __restrict__ bias,
                float* __restrict__ outp) {
    constexpr int CL    = C / VEC;      // lanes per edge row (12 or 10)
    constexpr int SLOTS = 64 / CL;      // edges per gather step (5 or 6)
    int n = blockIdx.x * 4 + (threadIdx.x >> 6);
    int lane = threadIdx.x & 63;
    int beg = rp[n], end = rp[n + 1];
    float adn = ad[n];

    // per-lane first-chunk edge + segment max
    int j0 = beg + lane;
    int sj = (j0 < end) ? csr_src[j0] : 0;
    float v = as[sj] + adn; v = (v >= 0.f) ? v : NEG_SLOPE * v;
    float mx = (j0 < end) ? v : -INFINITY;
    for (int j = j0 + 64; j < end; j += 64) {
        int s2 = csr_src[j];
        float v2 = as[s2] + adn; v2 = (v2 >= 0.f) ? v2 : NEG_SLOPE * v2;
        mx = fmaxf(mx, v2);
    }
    #pragma unroll
    for (int off = 32; off; off >>= 1) mx = fmaxf(mx, __shfl_xor(mx, off));

    const int slot = lane / CL;
    const int c    = lane - slot * CL;
    const bool slotok = slot < SLOTS;

    float acc[VEC];
    #pragma unroll
    for (int k = 0; k < VEC; ++k) acc[k] = 0.f;
    float s_lane = 0.f;

    for (int cb = beg; cb < end; cb += 64) {
        int cnt = min(64, end - cb);
        float w;
        if (cb == beg) {
            w = (j0 < end) ? __expf(v - mx) : 0.f;
        } else {
            int j = cb + lane;
            int s2 = (j < end) ? csr_src[j] : 0;
            float v2 = as[s2] + adn; v2 = (v2 >= 0.f) ? v2 : NEG_SLOPE * v2;
            w = (j < end) ? __expf(v2 - mx) : 0.f;
            sj = s2;
        }
        s_lane += w;

        for (int base = 0; base < cnt; base += SLOTS * UN) {
            #pragma unroll
            for (int u = 0; u < UN; ++u) {
                int jj = base + u * SLOTS + slot;
                bool act = slotok && (jj < cnt);
                int jjc = act ? jj : 0;
                int   srcu = __shfl(sj, jjc);
                float wu   = __shfl(w,  jjc);
                if (act) {
                    if constexpr (VEC == 8) {
                        int4 g = reinterpret_cast<const int4*>(hv)[(size_t)srcu * CL + c];
                        acc[0] = fmaf(wu, bfu_lo(g.x), acc[0]);
                        acc[1] = fmaf(wu, bfu_hi(g.x), acc[1]);
                        acc[2] = fmaf(wu, bfu_lo(g.y), acc[2]);
                        acc[3] = fmaf(wu, bfu_hi(g.y), acc[3]);
                        acc[4] = fmaf(wu, bfu_lo(g.z), acc[4]);
                        acc[5] = fmaf(wu, bfu_hi(g.z), acc[5]);
                        acc[6] = fmaf(wu, bfu_lo(g.w), acc[6]);
                        acc[7] = fmaf(wu, bfu_hi(g.w), acc[7]);
                    } else {
                        uint2 g = reinterpret_cast<const uint2*>(hv)[(size_t)srcu * CL + c];
                        acc[0] = fmaf(wu, bfu_lo(g.x), acc[0]);
                        acc[1] = fmaf(wu, bfu_hi(g.x), acc[1]);
                        acc[2] = fmaf(wu, bfu_lo(g.y), acc[2]);
                        acc[3] = fmaf(wu, bfu_hi(g.y), acc[3]);
                    }
                }
            }
        }
    }

    // fold slot accumulators into lanes [0, CL): gather from immutable acc
    float tot[VEC];
    #pragma unroll
    for (int k = 0; k < VEC; ++k) tot[k] = acc[k];
    #pragma unroll
    for (int s = 1; s < SLOTS; ++s) {
        int sl = (lane + CL * s) & 63;      // for lane<CL never wraps
        #pragma unroll
        for (int k = 0; k < VEC; ++k) tot[k] += __shfl(acc[k], sl);
    }
    float ssum = s_lane;
    #pragma unroll
    for (int off = 32; off; off >>= 1) ssum += __shfl_xor(ssum, off);
    float inv = 1.f / ssum;

    if (EPI == 0) {
        if (lane < CL) {
            const float* b = bias + lane * VEC;
            float4* o = reinterpret_cast<float4*>(outp) + (size_t)n * (C / 4) + lane * (VEC / 4);
            #pragma unroll
            for (int q = 0; q < VEC / 4; ++q) {
                float4 ov;
                ov.x = fmaxf(fmaf(tot[4*q+0], inv, b[4*q+0]), 0.f);
                ov.y = fmaxf(fmaf(tot[4*q+1], inv, b[4*q+1]), 0.f);
                ov.z = fmaxf(fmaf(tot[4*q+2], inv, b[4*q+2]), 0.f);
                ov.w = fmaxf(fmaf(tot[4*q+3], inv, b[4*q+3]), 0.f);
                o[q] = ov;
            }
        }
    } else {
        bool actw = lane < CL;
        float v0 = -INFINITY, v1 = -INFINITY, v2 = -INFINITY, v3 = -INFINITY;
        if (actw) {
            const float* b = bias + lane * 4;
            v0 = fmaf(tot[0], inv, b[0]); v1 = fmaf(tot[1], inv, b[1]);
            v2 = fmaf(tot[2], inv, b[2]); v3 = fmaf(tot[3], inv, b[3]);
        }
        float vm = fmaxf(fmaxf(v0, v1), fmaxf(v2, v3));
        #pragma unroll
        for (int off = 32; off; off >>= 1) vm = fmaxf(vm, __shfl_xor(vm, off));
        float es = actw ? (__expf(v0 - vm) + __expf(v1 - vm) +
                           __expf(v2 - vm) + __expf(v3 - vm)) : 0.f;
        #pragma unroll
        for (int off = 32; off; off >>= 1) es += __shfl_xor(es, off);
        float lse = vm + logf(es);
        if (actw) {
            float4 ov = make_float4(v0 - lse, v1 - lse, v2 - lse, v3 - lse);
            reinterpret_cast<float4*>(outp)[(size_t)n * (C / 4) + lane] = ov;
        }
    }
}

// ---------------- launch ----------------

extern "C" void kernel_launch(void* const* d_in, const int* in_sizes, int n_in,
                              void* d_out, int out_size, void* d_ws, size_t ws_size,
                              hipStream_t stream) {
    const float* x      = (const float*)d_in[0];
    const int*   ei     = (const int*)d_in[1];
    const float* W1     = (const float*)d_in[3];
    const float* a_src1 = (const float*)d_in[4];
    const float* a_dst1 = (const float*)d_in[5];
    const float* b1     = (const float*)d_in[6];
    const float* W2     = (const float*)d_in[7];
    const float* a_src2 = (const float*)d_in[8];
    const float* a_dst2 = (const float*)d_in[9];
    const float* b2     = (const float*)d_in[10];
    float* out = (float*)d_out;

    float* wsf = (float*)d_ws;
    size_t off = 0;
    float* x2  = wsf + off; off += (size_t)N_NODES * C_HID;   // fp32 layer-2 input
    float* as1 = wsf + off; off += N_NODES;
    float* ad1 = wsf + off; off += N_NODES;
    float* as2 = wsf + off; off += N_NODES;
    float* ad2 = wsf + off; off += N_NODES;
    unsigned short* h1 = (unsigned short*)(wsf + off); off += (size_t)N_NODES * C_HID / 2;
    unsigned short* h2 = (unsigned short*)(wsf + off); off += (size_t)N_NODES * C_OUT / 2;
    int* wsi     = (int*)(wsf + off);
    size_t ioff  = 0;
    int* deg     = wsi + ioff; ioff += N_NODES;
    int* row_ptr = wsi + ioff; ioff += N_NODES + 1;
    int* cursor  = wsi + ioff; ioff += N_NODES;
    int* csr_src = wsi + ioff; ioff += N_ETOT;
    int* bsum    = wsi + ioff; ioff += NSB;
    int* boff    = wsi + ioff; ioff += NSB;

    // CSR build (shared by both layers)
    k_initdeg<<<(N_NODES + 255) / 256, 256, 0, stream>>>(deg);
    k_hist<<<(N_EDGES + 255) / 256, 256, 0, stream>>>(ei, deg);
    k_scan1<<<NSB, 1024, 0, stream>>>(deg, row_ptr, bsum);
    k_scan2<<<1, 64, 0, stream>>>(bsum, boff, row_ptr);
    k_scan3<<<(N_NODES + 1023) / 1024, 1024, 0, stream>>>(row_ptr, boff, cursor);
    k_scatter<<<(N_ETOT + 255) / 256, 256, 0, stream>>>(ei, cursor, csr_src);

    // layer 1
    k_gemm<C_IN, C_HID, 32, 24, 8, 4><<<(N_NODES + 31) / 32, 192, 0, stream>>>(
        x, W1, a_src1, a_dst1, h1, as1, ad1);
    k_node_agg<C_HID, 8, 2, 0><<<N_NODES / 4, 256, 0, stream>>>(
        row_ptr, csr_src, as1, ad1, h1, b1, x2);

    // layer 2
    k_gemm<C_HID, C_OUT, 96, 10, 32, 2><<<(N_NODES + 63) / 64, 320, 0, stream>>>(
        x2, W2, a_src2, a_dst2, h2, as2, ad2);
    k_node_agg<C_OUT, 4, 2, 1><<<N_NODES / 4, 256, 0, stream>>>(
        row_ptr, csr_src, as2, ad2, h2, b2, out);
}

// Round 9
// 311.411 us; speedup vs baseline: 2.7261x; 1.0363x over previous
//
#include <hip/hip_runtime.h>
#include <math.h>

#define N_NODES 50000
#define N_EDGES 800000
#define N_ETOT  850000          // + self loops
#define C_IN    128
#define C_HID   96
#define C_OUT   40
#define NEG_SLOPE 0.2f
#define NSB ((N_NODES + 1023) / 1024)   // 49 scan blocks
#define NPART 8
#define PART_SZ ((N_NODES + NPART - 1) / NPART)   // 6250

// ---------------- bf16 helpers ----------------
__device__ __forceinline__ unsigned short f2bf(float f) {
    unsigned u = __float_as_uint(f);
    u = u + 0x7fffu + ((u >> 16) & 1u);     // round-to-nearest-even
    return (unsigned short)(u >> 16);
}
__device__ __forceinline__ float bfu_lo(unsigned g) { return __uint_as_float(g << 16); }
__device__ __forceinline__ float bfu_hi(unsigned g) { return __uint_as_float(g & 0xffff0000u); }

// ---------------- CSR build ----------------

__global__ void k_initdeg(int* __restrict__ deg) {
    int i = blockIdx.x * blockDim.x + threadIdx.x;
    if (i < N_NODES) deg[i] = 1;            // self loop
}

// dst-partitioned histogram: blocks with bid%NPART==p count only dst in partition p
// -> atomics on deg stay XCD-local (bid%8 ~ XCD with round-robin dispatch).
__global__ void k_hist(const int* __restrict__ ei, int* __restrict__ deg) {
    int p  = blockIdx.x & (NPART - 1);
    int qb = blockIdx.x / NPART;
    int nq = gridDim.x / NPART;
    int lo = p * PART_SZ, hi = min(N_NODES, lo + PART_SZ);
    int stride = nq * blockDim.x;
    for (int i = qb * blockDim.x + threadIdx.x; i < N_EDGES; i += stride) {
        int d = ei[N_EDGES + i];
        if (d >= lo && d < hi) atomicAdd(&deg[d], 1);
    }
}

// hierarchical exclusive scan: per-block scan -> scan of block sums -> add offsets
__global__ void k_scan1(const int* __restrict__ deg, int* __restrict__ rp,
                        int* __restrict__ bsum) {
    __shared__ int wsum[16];
    int t = threadIdx.x, lane = t & 63, w = t >> 6;
    int i = blockIdx.x * 1024 + t;
    int v = (i < N_NODES) ? deg[i] : 0;
    int inc = v;
    #pragma unroll
    for (int off = 1; off < 64; off <<= 1) {
        int u = __shfl_up(inc, off);
        if (lane >= off) inc += u;
    }
    if (lane == 63) wsum[w] = inc;
    __syncthreads();
    if (w == 0) {
        int sv = (lane < 16) ? wsum[lane] : 0;
        #pragma unroll
        for (int off = 1; off < 16; off <<= 1) {
            int u = __shfl_up(sv, off);
            if (lane >= off) sv += u;
        }
        if (lane < 16) wsum[lane] = sv;       // inclusive over waves
    }
    __syncthreads();
    int exc = ((w == 0) ? 0 : wsum[w - 1]) + inc - v;
    if (i < N_NODES) rp[i] = exc;
    if (t == 0) bsum[blockIdx.x] = wsum[15];
}

__global__ void k_scan2(const int* __restrict__ bsum, int* __restrict__ boff,
                        int* __restrict__ rp) {
    int lane = threadIdx.x;   // 64 threads
    int v = (lane < NSB) ? bsum[lane] : 0;
    int inc = v;
    #pragma unroll
    for (int off = 1; off < 64; off <<= 1) {
        int u = __shfl_up(inc, off);
        if (lane >= off) inc += u;
    }
    if (lane < NSB) boff[lane] = inc - v;
    if (lane == 63) rp[N_NODES] = inc;        // total == N_ETOT
}

__global__ void k_scan3(int* __restrict__ rp, const int* __restrict__ boff,
                        int* __restrict__ cursor) {
    int i = blockIdx.x * blockDim.x + threadIdx.x;
    if (i < N_NODES) {
        int v = rp[i] + boff[i >> 10];
        rp[i] = v; cursor[i] = v;
    }
}

// dst-partitioned scatter: partition p's cursor range and its contiguous csr_src
// slice are written only by bid%NPART==p blocks -> lines stay in one L2, write
// back once (was: 54.9 MB HBM write-through = 850K x 64B cross-XCD lines).
__global__ void k_scatter(const int* __restrict__ ei, int* __restrict__ cursor,
                          int* __restrict__ csr_src) {
    int p  = blockIdx.x & (NPART - 1);
    int qb = blockIdx.x / NPART;
    int nq = gridDim.x / NPART;
    int lo = p * PART_SZ, hi = min(N_NODES, lo + PART_SZ);
    int stride = nq * blockDim.x;
    for (int i = qb * blockDim.x + threadIdx.x; i < N_ETOT; i += stride) {
        int src, dst;
        if (i < N_EDGES) { src = ei[i]; dst = ei[N_EDGES + i]; }   // coalesced reads
        else             { src = dst = i - N_EDGES; }
        if (dst >= lo && dst < hi) {
            int pos = atomicAdd(&cursor[dst], 1);
            csr_src[pos] = src;
        }
    }
}

// ---------------- tiled GEMM + fused alpha dots, bf16 H output ----------------
// H[N, COUT](bf16) = X[N, CIN] @ W[CIN, COUT]; as[n]=H[n]·asrc; ad[n]=H[n]·adst (fp32)

template<int CIN, int COUT, int KH, int CT, int NT, int NP>
__global__ __launch_bounds__(CT * NT)
void k_gemm(const float* __restrict__ X, const float* __restrict__ W,
            const float* __restrict__ asrc, const float* __restrict__ adst,
            unsigned short* __restrict__ Hb, float* __restrict__ as, float* __restrict__ ad) {
    constexpr int NPB = NT * NP;
    constexpr int BLK = CT * NT;
    constexpr int KQ  = CIN / 4;
    constexpr int CQ  = COUT / 4;
    __shared__ float xs[NPB][CIN + 1];
    __shared__ float4 Ws4[KH][CQ + 1];     // +1 f4 pad: row-to-row bank shift
    __shared__ float red[NPB * 2];
    const int t  = threadIdx.x;
    const int nb = blockIdx.x * NPB;

    for (int idx = t; idx < NPB * 2; idx += BLK) red[idx] = 0.f;

    for (int idx = t; idx < NPB * KQ; idx += BLK) {
        int n = idx / KQ, kq = idx - n * KQ;
        float4 v = make_float4(0.f, 0.f, 0.f, 0.f);
        if (nb + n < N_NODES)
            v = reinterpret_cast<const float4*>(X)[(size_t)(nb + n) * KQ + kq];
        xs[n][4 * kq + 0] = v.x; xs[n][4 * kq + 1] = v.y;
        xs[n][4 * kq + 2] = v.z; xs[n][4 * kq + 3] = v.w;
    }

    const int ct = t % CT, nt = t / CT;
    float acc[NP][4] = {};

    for (int kb = 0; kb < CIN; kb += KH) {
        __syncthreads();                    // xs ready / Ws reusable
        for (int idx = t; idx < KH * CQ; idx += BLK) {
            int kk = idx / CQ, c4 = idx - kk * CQ;
            Ws4[kk][c4] = reinterpret_cast<const float4*>(W)[(size_t)(kb + kk) * CQ + c4];
        }
        __syncthreads();
        #pragma unroll 4
        for (int kk = 0; kk < KH; ++kk) {
            float4 wv = Ws4[kk][ct];
            #pragma unroll
            for (int i = 0; i < NP; ++i) {
                float xv = xs[nt * NP + i][kb + kk];
                acc[i][0] = fmaf(xv, wv.x, acc[i][0]);
                acc[i][1] = fmaf(xv, wv.y, acc[i][1]);
                acc[i][2] = fmaf(xv, wv.z, acc[i][2]);
                acc[i][3] = fmaf(xv, wv.w, acc[i][3]);
            }
        }
    }

    // epilogue: bf16 H write + alpha partial dots via LDS float atomics (fp32)
    float a0 = asrc[4*ct], a1 = asrc[4*ct+1], a2 = asrc[4*ct+2], a3 = asrc[4*ct+3];
    float d0 = adst[4*ct], d1 = adst[4*ct+1], d2 = adst[4*ct+2], d3 = adst[4*ct+3];
    #pragma unroll
    for (int i = 0; i < NP; ++i) {
        int n = nb + nt * NP + i;
        float pa = acc[i][0]*a0 + acc[i][1]*a1 + acc[i][2]*a2 + acc[i][3]*a3;
        float pd = acc[i][0]*d0 + acc[i][1]*d1 + acc[i][2]*d2 + acc[i][3]*d3;
        atomicAdd(&red[2 * (nt * NP + i)    ], pa);
        atomicAdd(&red[2 * (nt * NP + i) + 1], pd);
        if (n < N_NODES) {
            ushort4 o;
            o.x = f2bf(acc[i][0]); o.y = f2bf(acc[i][1]);
            o.z = f2bf(acc[i][2]); o.w = f2bf(acc[i][3]);
            reinterpret_cast<ushort4*>(Hb)[(size_t)n * CQ + ct] = o;
        }
    }
    __syncthreads();
    for (int idx = t; idx < NPB; idx += BLK) {
        int n = nb + idx;
        if (n < N_NODES) { as[n] = red[2 * idx]; ad[n] = red[2 * idx + 1]; }
    }
}

// ---------------- fused segment softmax + aggregation, one wave per dst ----------------
// bf16 h gather. Per 64-edge chunk: all lanes compute w=exp(leaky(as+ad)-mx) once,
// then gather distributes src/w by shfl. VEC channels per lane; SLOTS edges in parallel.
// EPI 0: out = relu(agg + bias); EPI 1: out = log_softmax(agg + bias)

template<int C, int VEC, int UN, int EPI>
__global__ __launch_bounds__(256)
void k_node_agg(const int* __restrict__ rp, const int* __restrict__ csr_src,
                const float* __restrict__ as, const float* __restrict__ ad,
                const void* __restrict__ hv, const float* __restrict__ bias,
                float* __restrict__ outp) {
    constexpr int CL    = C / VEC;      // lanes per edge row (12 or 10)
    constexpr int SLOTS = 64 / CL;      // edges per gather step (5 or 6)
    int n = blockIdx.x * 4 + (threadIdx.x >> 6);
    int lane = threadIdx.x & 63;
    int beg = rp[n], end = rp[n + 1];
    float adn = ad[n];

    // per-lane first-chunk edge + segment max
    int j0 = beg + lane;
    int sj = (j0 < end) ? csr_src[j0] : 0;
    float v = as[sj] + adn; v = (v >= 0.f) ? v : NEG_SLOPE * v;
    float mx = (j0 < end) ? v : -INFINITY;
    for (int j = j0 + 64; j < end; j += 64) {
        int s2 = csr_src[j];
        float v2 = as[s2] + adn; v2 = (v2 >= 0.f) ? v2 : NEG_SLOPE * v2;
        mx = fmaxf(mx, v2);
    }
    #pragma unroll
    for (int off = 32; off; off >>= 1) mx = fmaxf(mx, __shfl_xor(mx, off));

    const int slot = lane / CL;
    const int c    = lane - slot * CL;
    const bool slotok = slot < SLOTS;

    float acc[VEC];
    #pragma unroll
    for (int k = 0; k < VEC; ++k) acc[k] = 0.f;
    float s_lane = 0.f;

    for (int cb = beg; cb < end; cb += 64) {
        int cnt = min(64, end - cb);
        float w;
        if (cb == beg) {
            w = (j0 < end) ? __expf(v - mx) : 0.f;
        } else {
            int j = cb + lane;
            int s2 = (j < end) ? csr_src[j] : 0;
            float v2 = as[s2] + adn; v2 = (v2 >= 0.f) ? v2 : NEG_SLOPE * v2;
            w = (j < end) ? __expf(v2 - mx) : 0.f;
            sj = s2;
        }
        s_lane += w;

        for (int base = 0; base < cnt; base += SLOTS * UN) {
            #pragma unroll
            for (int u = 0; u < UN; ++u) {
                int jj = base + u * SLOTS + slot;
                bool act = slotok && (jj < cnt);
                int jjc = act ? jj : 0;
                int   srcu = __shfl(sj, jjc);
                float wu   = __shfl(w,  jjc);
                if (act) {
                    if constexpr (VEC == 8) {
                        int4 g = reinterpret_cast<const int4*>(hv)[(size_t)srcu * CL + c];
                        acc[0] = fmaf(wu, bfu_lo(g.x), acc[0]);
                        acc[1] = fmaf(wu, bfu_hi(g.x), acc[1]);
                        acc[2] = fmaf(wu, bfu_lo(g.y), acc[2]);
                        acc[3] = fmaf(wu, bfu_hi(g.y), acc[3]);
                        acc[4] = fmaf(wu, bfu_lo(g.z), acc[4]);
                        acc[5] = fmaf(wu, bfu_hi(g.z), acc[5]);
                        acc[6] = fmaf(wu, bfu_lo(g.w), acc[6]);
                        acc[7] = fmaf(wu, bfu_hi(g.w), acc[7]);
                    } else {
                        uint2 g = reinterpret_cast<const uint2*>(hv)[(size_t)srcu * CL + c];
                        acc[0] = fmaf(wu, bfu_lo(g.x), acc[0]);
                        acc[1] = fmaf(wu, bfu_hi(g.x), acc[1]);
                        acc[2] = fmaf(wu, bfu_lo(g.y), acc[2]);
                        acc[3] = fmaf(wu, bfu_hi(g.y), acc[3]);
                    }
                }
            }
        }
    }

    // fold slot accumulators into lanes [0, CL): gather from immutable acc
    float tot[VEC];
    #pragma unroll
    for (int k = 0; k < VEC; ++k) tot[k] = acc[k];
    #pragma unroll
    for (int s = 1; s < SLOTS; ++s) {
        int sl = (lane + CL * s) & 63;      // for lane<CL never wraps
        #pragma unroll
        for (int k = 0; k < VEC; ++k) tot[k] += __shfl(acc[k], sl);
    }
    float ssum = s_lane;
    #pragma unroll
    for (int off = 32; off; off >>= 1) ssum += __shfl_xor(ssum, off);
    float inv = 1.f / ssum;

    if (EPI == 0) {
        if (lane < CL) {
            const float* b = bias + lane * VEC;
            float4* o = reinterpret_cast<float4*>(outp) + (size_t)n * (C / 4) + lane * (VEC / 4);
            #pragma unroll
            for (int q = 0; q < VEC / 4; ++q) {
                float4 ov;
                ov.x = fmaxf(fmaf(tot[4*q+0], inv, b[4*q+0]), 0.f);
                ov.y = fmaxf(fmaf(tot[4*q+1], inv, b[4*q+1]), 0.f);
                ov.z = fmaxf(fmaf(tot[4*q+2], inv, b[4*q+2]), 0.f);
                ov.w = fmaxf(fmaf(tot[4*q+3], inv, b[4*q+3]), 0.f);
                o[q] = ov;
            }
        }
    } else {
        bool actw = lane < CL;
        float v0 = -INFINITY, v1 = -INFINITY, v2 = -INFINITY, v3 = -INFINITY;
        if (actw) {
            const float* b = bias + lane * 4;
            v0 = fmaf(tot[0], inv, b[0]); v1 = fmaf(tot[1], inv, b[1]);
            v2 = fmaf(tot[2], inv, b[2]); v3 = fmaf(tot[3], inv, b[3]);
        }
        float vm = fmaxf(fmaxf(v0, v1), fmaxf(v2, v3));
        #pragma unroll
        for (int off = 32; off; off >>= 1) vm = fmaxf(vm, __shfl_xor(vm, off));
        float es = actw ? (__expf(v0 - vm) + __expf(v1 - vm) +
                           __expf(v2 - vm) + __expf(v3 - vm)) : 0.f;
        #pragma unroll
        for (int off = 32; off; off >>= 1) es += __shfl_xor(es, off);
        float lse = vm + logf(es);
        if (actw) {
            float4 ov = make_float4(v0 - lse, v1 - lse, v2 - lse, v3 - lse);
            reinterpret_cast<float4*>(outp)[(size_t)n * (C / 4) + lane] = ov;
        }
    }
}

// ---------------- launch ----------------

extern "C" void kernel_launch(void* const* d_in, const int* in_sizes, int n_in,
                              void* d_out, int out_size, void* d_ws, size_t ws_size,
                              hipStream_t stream) {
    const float* x      = (const float*)d_in[0];
    const int*   ei     = (const int*)d_in[1];
    const float* W1     = (const float*)d_in[3];
    const float* a_src1 = (const float*)d_in[4];
    const float* a_dst1 = (const float*)d_in[5];
    const float* b1     = (const float*)d_in[6];
    const float* W2     = (const float*)d_in[7];
    const float* a_src2 = (const float*)d_in[8];
    const float* a_dst2 = (const float*)d_in[9];
    const float* b2     = (const float*)d_in[10];
    float* out = (float*)d_out;

    float* wsf = (float*)d_ws;
    size_t off = 0;
    float* x2  = wsf + off; off += (size_t)N_NODES * C_HID;   // fp32 layer-2 input
    float* as1 = wsf + off; off += N_NODES;
    float* ad1 = wsf + off; off += N_NODES;
    float* as2 = wsf + off; off += N_NODES;
    float* ad2 = wsf + off; off += N_NODES;
    unsigned short* h1 = (unsigned short*)(wsf + off); off += (size_t)N_NODES * C_HID / 2;
    unsigned short* h2 = (unsigned short*)(wsf + off); off += (size_t)N_NODES * C_OUT / 2;
    int* wsi     = (int*)(wsf + off);
    size_t ioff  = 0;
    int* deg     = wsi + ioff; ioff += N_NODES;
    int* row_ptr = wsi + ioff; ioff += N_NODES + 1;
    int* cursor  = wsi + ioff; ioff += N_NODES;
    int* csr_src = wsi + ioff; ioff += N_ETOT;
    int* bsum    = wsi + ioff; ioff += NSB;
    int* boff    = wsi + ioff; ioff += NSB;

    // CSR build (shared by both layers), dst-partitioned for XCD locality
    k_initdeg<<<(N_NODES + 255) / 256, 256, 0, stream>>>(deg);
    k_hist<<<2048, 256, 0, stream>>>(ei, deg);
    k_scan1<<<NSB, 1024, 0, stream>>>(deg, row_ptr, bsum);
    k_scan2<<<1, 64, 0, stream>>>(bsum, boff, row_ptr);
    k_scan3<<<(N_NODES + 1023) / 1024, 1024, 0, stream>>>(row_ptr, boff, cursor);
    k_scatter<<<2048, 256, 0, stream>>>(ei, cursor, csr_src);

    // layer 1
    k_gemm<C_IN, C_HID, 32, 24, 8, 4><<<(N_NODES + 31) / 32, 192, 0, stream>>>(
        x, W1, a_src1, a_dst1, h1, as1, ad1);
    k_node_agg<C_HID, 8, 2, 0><<<N_NODES / 4, 256, 0, stream>>>(
        row_ptr, csr_src, as1, ad1, h1, b1, x2);

    // layer 2
    k_gemm<C_HID, C_OUT, 96, 10, 32, 2><<<(N_NODES + 63) / 64, 320, 0, stream>>>(
        x2, W2, a_src2, a_dst2, h2, as2, ad2);
    k_node_agg<C_OUT, 4, 2, 1><<<N_NODES / 4, 256, 0, stream>>>(
        row_ptr, csr_src, as2, ad2, h2, b2, out);
}